// Round 8
// baseline (442.364 us; speedup 1.0000x reference)
//
#include <hip/hip_runtime.h>
#include <hip/hip_bf16.h>
#include <math.h>

#define NN 8192
#define DD 256
#define FF 64
#define WPB 4                    // waves per k_attn block
#define ROWS 16                  // i-rows per k_attn block
#define CPW (NN / 32 / WPB)      // 32-j chunks per wave = 64

typedef __attribute__((ext_vector_type(8))) short bf16x8;
typedef __attribute__((ext_vector_type(4))) float f32x4;

__device__ __forceinline__ ushort f2bf(float x) {
  union { __hip_bfloat16 b; ushort s; } u;
  u.b = __float2bfloat16(x);
  return u.s;
}

// ---------------------------------------------------------------------------
// k_pre: W [256][64] f32 -> WT [64][256] bf16.
// ---------------------------------------------------------------------------
__global__ __launch_bounds__(256) void k_pre(const float* __restrict__ W,
                                             ushort* __restrict__ WT) {
  const int e4 = (blockIdx.x * 256 + threadIdx.x) * 4;  // element = k*64 + d
  const float4 wv = *(const float4*)(W + e4);
  const int k = e4 >> 6, d = e4 & 63;
  WT[(d + 0) * DD + k] = f2bf(wv.x);
  WT[(d + 1) * DD + k] = f2bf(wv.y);
  WT[(d + 2) * DD + k] = f2bf(wv.z);
  WT[(d + 3) * DD + k] = f2bf(wv.w);
}

// ---------------------------------------------------------------------------
// k_mask: adj (int32 0/1, 268 MB) -> bitmask (8 MB). Pure streaming kernel
// (verified round 5). Bit j of dword m == adj element 32m + j.
// ---------------------------------------------------------------------------
__global__ __launch_bounds__(256) void k_mask(const int* __restrict__ adj,
                                              uint* __restrict__ mask) {
  const size_t nquad = (size_t)NN * NN / 4;
  const size_t stride = (size_t)gridDim.x * 256;
  const int lane = threadIdx.x & 63;
  for (size_t q = (size_t)blockIdx.x * 256 + threadIdx.x; q < nquad; q += stride) {
    const int4 v = ((const int4*)adj)[q];
    uint nib = (uint)(v.x & 1) | ((uint)(v.y & 1) << 1) |
               ((uint)(v.z & 1) << 2) | ((uint)(v.w & 1) << 3);
    uint b = nib | ((uint)__shfl_xor((int)nib, 1) << 4);   // byte @ even lanes
    b |= (uint)__shfl_xor((int)b, 2) << 8;                 // 16b @ lanes%4==0
    b |= (uint)__shfl_xor((int)b, 4) << 16;                // 32b @ lanes%8==0
    if ((lane & 7) == 0) mask[q >> 3] = b;
  }
}

// ---------------------------------------------------------------------------
// k_h: h = feat @ W via MFMA (verified rounds 3-6). Wave w = d-slab
// [w*16,w*16+16). hTf stored in MFMA fragment order:
// hTf[((f*256 + j32)*64 + kg*16 + il)*8 + e] = hT[f*16+il][j32*32 + kg*8 + e].
// Epilogue stores exp-factor tables E1=exp(s1), F1=exp(.2 s1), E2=exp(s2),
// F2=exp(.2 s2)  (s1 = h@a1, s2 = h@a2 from the f32 accumulators).
// ---------------------------------------------------------------------------
__global__ __launch_bounds__(256) void k_h(
    const float* __restrict__ feat, const ushort* __restrict__ WT,
    const float* __restrict__ a, ushort* __restrict__ hTf,
    float* __restrict__ E1, float* __restrict__ F1,
    float* __restrict__ E2, float* __restrict__ F2) {
  __shared__ float sp1[4][16], sp2[4][16];
  const int t = threadIdx.x, lane = t & 63, w = t >> 6;
  const int il = lane & 15, kg = lane >> 4;
  const int ibase = blockIdx.x * 16;
  const int d = w * 16 + il;
  const float* frow = feat + (size_t)(ibase + il) * DD + kg * 8;
  const ushort* wrow = WT + (size_t)d * DD + kg * 8;
  f32x4 acc = {0.f, 0.f, 0.f, 0.f};
#pragma unroll
  for (int k0 = 0; k0 < DD; k0 += 32) {
    const float4 fa = *(const float4*)(frow + k0);
    const float4 fb = *(const float4*)(frow + k0 + 4);
    bf16x8 av;
    av[0] = f2bf(fa.x); av[1] = f2bf(fa.y); av[2] = f2bf(fa.z); av[3] = f2bf(fa.w);
    av[4] = f2bf(fb.x); av[5] = f2bf(fb.y); av[6] = f2bf(fb.z); av[7] = f2bf(fb.w);
    const bf16x8 bv = *(const bf16x8*)(wrow + k0);
    acc = __builtin_amdgcn_mfma_f32_16x16x32_bf16(av, bv, acc, 0, 0, 0);
  }
  ushort4 hv;
  hv.x = f2bf(acc[0]);
  hv.y = f2bf(acc[1]);
  hv.z = f2bf(acc[2]);
  hv.w = f2bf(acc[3]);
  {
    const int i0q = ibase + kg * 4;  // 4-aligned "j" index of hTf
    const size_t hb = ((size_t)(w * 256 + (i0q >> 5)) * 64 +
                       ((i0q >> 3) & 3) * 16 + il) * 8 + (i0q & 7);
    *(ushort4*)(hTf + hb) = hv;
  }
  const float a1v = a[d], a2v = a[FF + d];
#pragma unroll
  for (int r = 0; r < 4; ++r) {
    float v1 = acc[r] * a1v;
    float v2 = acc[r] * a2v;
#pragma unroll
    for (int m = 1; m <= 8; m <<= 1) {
      v1 += __shfl_xor(v1, m);
      v2 += __shfl_xor(v2, m);
    }
    if (il == 0) {
      sp1[w][kg * 4 + r] = v1;
      sp2[w][kg * 4 + r] = v2;
    }
  }
  __syncthreads();
  if (t < 16) {
    const float s1 = sp1[0][t] + sp1[1][t] + sp1[2][t] + sp1[3][t];
    const float s2 = sp2[0][t] + sp2[1][t] + sp2[2][t] + sp2[3][t];
    E1[ibase + t] = __expf(s1);
    F1[ibase + t] = __expf(0.2f * s1);
    E2[ibase + t] = __expf(s2);
    F2[ibase + t] = __expf(0.2f * s2);
  }
}

// ---------------------------------------------------------------------------
// k_attn: register-direct P + PV MFMA. NO LDS / NO counter drains in loop.
// Block = 16 rows x 4 waves (256 thr, grid 512); wave w owns j-window
// [w*2048,(w+1)*2048) as 64 chunks of 32 j.
// Per chunk, lane (il,kg) builds its B-fragment directly:
//   pb[e] = adjbit(row, j) ? max(E1[row]*E2[j], F1[row]*F2[j]) : 0
// (= exp(lrelu(s1+s2)) masked; exp monotone => lrelu commutes to max; the
// uniform softmax shift cancels in normalization). Sources: mask dword
// (4-lane shared, L1-hot), E2/F2 float4s (16-lane shared, L1-hot).
// l-sum via ones-A MFMA from the SAME bf16 p. hTf A-frags coalesced 16B/lane.
// Epilogue: per-wave tr/l to LDS, syncthreads, 4-way combine, norm+ELU, store.
// ---------------------------------------------------------------------------
__global__ __launch_bounds__(256) void k_attn(
    const uint* __restrict__ mask, const ushort* __restrict__ hTf,
    const float* __restrict__ E1g, const float* __restrict__ F1g,
    const float* __restrict__ E2g, const float* __restrict__ F2g,
    float* __restrict__ out) {
  __shared__ float tr[WPB][16][65];
  __shared__ float lw[WPB][16];
  const int t = threadIdx.x;
  const int lane = t & 63, w = t >> 6;
  const int il = lane & 15, kg = lane >> 4;
  const int rbase = blockIdx.x * ROWS;
  const int row = rbase + il;
  const float e1 = E1g[row], f1 = F1g[row];
  const uint* mp = mask + (size_t)row * (NN / 32) + w * CPW;
  const int jb0 = w * CPW * 32 + kg * 8;

  bf16x8 ones;
#pragma unroll
  for (int e = 0; e < 8; ++e) ones[e] = (short)0x3F80;  // bf16 1.0

  f32x4 acc[4] = {{0,0,0,0},{0,0,0,0},{0,0,0,0},{0,0,0,0}};
  f32x4 accl = {0.f, 0.f, 0.f, 0.f};

#pragma unroll 4
  for (int c = 0; c < CPW; ++c) {
    const uint bits = mp[c] >> (kg * 8);
    const int jo = jb0 + c * 32;
    const float4 e2a = *(const float4*)(E2g + jo);
    const float4 e2b = *(const float4*)(E2g + jo + 4);
    const float4 f2a = *(const float4*)(F2g + jo);
    const float4 f2b = *(const float4*)(F2g + jo + 4);
    bf16x8 pb;
    pb[0] = (bits & 1u)   ? (short)f2bf(fmaxf(e1 * e2a.x, f1 * f2a.x)) : (short)0;
    pb[1] = (bits & 2u)   ? (short)f2bf(fmaxf(e1 * e2a.y, f1 * f2a.y)) : (short)0;
    pb[2] = (bits & 4u)   ? (short)f2bf(fmaxf(e1 * e2a.z, f1 * f2a.z)) : (short)0;
    pb[3] = (bits & 8u)   ? (short)f2bf(fmaxf(e1 * e2a.w, f1 * f2a.w)) : (short)0;
    pb[4] = (bits & 16u)  ? (short)f2bf(fmaxf(e1 * e2b.x, f1 * f2b.x)) : (short)0;
    pb[5] = (bits & 32u)  ? (short)f2bf(fmaxf(e1 * e2b.y, f1 * f2b.y)) : (short)0;
    pb[6] = (bits & 64u)  ? (short)f2bf(fmaxf(e1 * e2b.z, f1 * f2b.z)) : (short)0;
    pb[7] = (bits & 128u) ? (short)f2bf(fmaxf(e1 * e2b.w, f1 * f2b.w)) : (short)0;
    accl = __builtin_amdgcn_mfma_f32_16x16x32_bf16(ones, pb, accl, 0, 0, 0);
    const int j32 = w * CPW + c;
#pragma unroll
    for (int f = 0; f < 4; ++f) {
      const bf16x8 hv =
          *(const bf16x8*)(hTf + ((size_t)(f * 256 + j32) * 64 + lane) * 8);
      acc[f] = __builtin_amdgcn_mfma_f32_16x16x32_bf16(hv, pb, acc[f], 0, 0, 0);
    }
  }
  // lane holds i = rbase+il (col n), d = f*16 + kg*4 + r (row m)
#pragma unroll
  for (int f = 0; f < 4; ++f)
#pragma unroll
    for (int r = 0; r < 4; ++r) tr[w][il][f * 16 + kg * 4 + r] = acc[f][r];
  if (lane < 16) lw[w][il] = accl[0];  // l_i (same for all m-rows/regs)
  __syncthreads();
  // 4-way combine + normalize + ELU, coalesced
#pragma unroll
  for (int k = 0; k < (ROWS * FF) / 256; ++k) {
    const int idx = t + k * 256;
    const int r = idx >> 6, d = idx & 63;
    float s = 0.f, L = 0.f;
#pragma unroll
    for (int ww = 0; ww < WPB; ++ww) {
      s += tr[ww][r][d];
      L += lw[ww][r];
    }
    const float x = s / fmaxf(L, 1e-30f);
    out[(size_t)(rbase + r) * FF + d] = x > 0.f ? x : expm1f(x);
  }
}

extern "C" void kernel_launch(void* const* d_in, const int* in_sizes, int n_in,
                              void* d_out, int out_size, void* d_ws, size_t ws_size,
                              hipStream_t stream) {
  const float* feat = (const float*)d_in[0];
  const int* adj = (const int*)d_in[1];
  const float* W = (const float*)d_in[2];
  const float* a = (const float*)d_in[3];
  float* out = (float*)d_out;

  ushort* hTf = (ushort*)d_ws;                      // 64*8192 bf16 = 1 MB
  ushort* WT = hTf + (size_t)FF * NN;               // 64*256 bf16 = 32 KB
  float* E1 = (float*)(WT + (size_t)FF * DD);       // 8192 f32 each
  float* F1 = E1 + NN;
  float* E2 = F1 + NN;
  float* F2 = E2 + NN;
  uint* mask = (uint*)(F2 + NN);                    // 8 MB bitmask

  hipLaunchKernelGGL(k_pre, dim3(DD * FF / 1024), dim3(256), 0, stream, W, WT);
  hipLaunchKernelGGL(k_h, dim3(NN / 16), dim3(256), 0, stream, feat, WT, a, hTf,
                     E1, F1, E2, F2);
  hipLaunchKernelGGL(k_mask, dim3(2048), dim3(256), 0, stream, adj, mask);
  hipLaunchKernelGGL(k_attn, dim3(NN / ROWS), dim3(256), 0, stream,
                     mask, hTf, E1, F1, E2, F2, out);
}

// Round 10
// 425.295 us; speedup vs baseline: 1.0401x; 1.0401x over previous
//
#include <hip/hip_runtime.h>
#include <hip/hip_bf16.h>
#include <math.h>

#define NN 8192
#define DD 256
#define FF 64
#define WPB 8                 // waves per k_attn block
#define ROWS 16               // i-rows per k_attn block
#define CPW 32                // 32-j chunks per wave (j-window = 1024)
#define MPITCH 257            // mask LDS row pitch in dwords (pad breaks bank aliasing)

typedef __attribute__((ext_vector_type(8))) short bf16x8;
typedef __attribute__((ext_vector_type(4))) float f32x4;

__device__ __forceinline__ ushort f2bf(float x) {
  union { __hip_bfloat16 b; ushort s; } u;
  u.b = __float2bfloat16(x);
  return u.s;
}

// ---------------------------------------------------------------------------
// k_pre: W [256][64] f32 -> WT [64][256] bf16.
// ---------------------------------------------------------------------------
__global__ __launch_bounds__(256) void k_pre(const float* __restrict__ W,
                                             ushort* __restrict__ WT) {
  const int e4 = (blockIdx.x * 256 + threadIdx.x) * 4;  // element = k*64 + d
  const float4 wv = *(const float4*)(W + e4);
  const int k = e4 >> 6, d = e4 & 63;
  WT[(d + 0) * DD + k] = f2bf(wv.x);
  WT[(d + 1) * DD + k] = f2bf(wv.y);
  WT[(d + 2) * DD + k] = f2bf(wv.z);
  WT[(d + 3) * DD + k] = f2bf(wv.w);
}

// ---------------------------------------------------------------------------
// k_h: h = feat @ W via MFMA (verified rounds 3-8). Wave w = d-slab
// [w*16,w*16+16). hTf stored in MFMA fragment order:
// hTf[((f*256 + j32)*64 + kg*16 + il)*8 + e] = hT[f*16+il][j32*32 + kg*8 + e].
// Epilogue stores exp-factor tables E1=exp(s1), F1=exp(.2 s1), E2=exp(s2),
// F2=exp(.2 s2)  (s1 = h@a1, s2 = h@a2 from the f32 accumulators).
// ---------------------------------------------------------------------------
__global__ __launch_bounds__(256) void k_h(
    const float* __restrict__ feat, const ushort* __restrict__ WT,
    const float* __restrict__ a, ushort* __restrict__ hTf,
    float* __restrict__ E1, float* __restrict__ F1,
    float* __restrict__ E2, float* __restrict__ F2) {
  __shared__ float sp1[4][16], sp2[4][16];
  const int t = threadIdx.x, lane = t & 63, w = t >> 6;
  const int il = lane & 15, kg = lane >> 4;
  const int ibase = blockIdx.x * 16;
  const int d = w * 16 + il;
  const float* frow = feat + (size_t)(ibase + il) * DD + kg * 8;
  const ushort* wrow = WT + (size_t)d * DD + kg * 8;
  f32x4 acc = {0.f, 0.f, 0.f, 0.f};
#pragma unroll
  for (int k0 = 0; k0 < DD; k0 += 32) {
    const float4 fa = *(const float4*)(frow + k0);
    const float4 fb = *(const float4*)(frow + k0 + 4);
    bf16x8 av;
    av[0] = f2bf(fa.x); av[1] = f2bf(fa.y); av[2] = f2bf(fa.z); av[3] = f2bf(fa.w);
    av[4] = f2bf(fb.x); av[5] = f2bf(fb.y); av[6] = f2bf(fb.z); av[7] = f2bf(fb.w);
    const bf16x8 bv = *(const bf16x8*)(wrow + k0);
    acc = __builtin_amdgcn_mfma_f32_16x16x32_bf16(av, bv, acc, 0, 0, 0);
  }
  ushort4 hv;
  hv.x = f2bf(acc[0]);
  hv.y = f2bf(acc[1]);
  hv.z = f2bf(acc[2]);
  hv.w = f2bf(acc[3]);
  {
    const int i0q = ibase + kg * 4;  // 4-aligned "j" index of hTf
    const size_t hb = ((size_t)(w * 256 + (i0q >> 5)) * 64 +
                       ((i0q >> 3) & 3) * 16 + il) * 8 + (i0q & 7);
    *(ushort4*)(hTf + hb) = hv;
  }
  const float a1v = a[d], a2v = a[FF + d];
#pragma unroll
  for (int r = 0; r < 4; ++r) {
    float v1 = acc[r] * a1v;
    float v2 = acc[r] * a2v;
#pragma unroll
    for (int m = 1; m <= 8; m <<= 1) {
      v1 += __shfl_xor(v1, m);
      v2 += __shfl_xor(v2, m);
    }
    if (il == 0) {
      sp1[w][kg * 4 + r] = v1;
      sp2[w][kg * 4 + r] = v2;
    }
  }
  __syncthreads();
  if (t < 16) {
    const float s1 = sp1[0][t] + sp1[1][t] + sp1[2][t] + sp1[3][t];
    const float s2 = sp2[0][t] + sp2[1][t] + sp2[2][t] + sp2[3][t];
    E1[ibase + t] = __expf(s1);
    F1[ibase + t] = __expf(0.2f * s1);
    E2[ibase + t] = __expf(s2);
    F2[ibase + t] = __expf(0.2f * s2);
  }
}

// ---------------------------------------------------------------------------
// k_attn (fused): adj->LDS-bitmask streaming + register-direct P + PV MFMA.
// Grid 512 x 512 thr (8 waves), 16 rows/block, launch_bounds(512,4) ->
// 2 blocks/CU (50% occupancy). One barrier total in the main path.
// Phase 1: block streams its 512KB adj slice coalesced (int4, 1KB/wave-instr),
//   shfl-assembles bit dwords (verified round 5), writes 16KB padded LDS mask.
// Phase 2: wave w owns j-window [w*1024,(w+1)*1024) as 32 chunks of 32 j.
//   Per chunk, lane (il,kg) builds its B-fragment in registers:
//     pb[e] = bit(row,j) ? max(E1[row]*E2[j], F1[row]*F2[j]) : 0
//   (= exp(lrelu(s1+s2)), exp monotone => lrelu commutes to max; uniform
//   softmax shift cancels). bits via conflict-free ds_read_b32 (pad 257),
//   E2/F2 L1-hot broadcast float4s, hTf A-frags coalesced 16B/lane.
//   l-sum via ones-A MFMA from the SAME bf16 p. No barriers, no drains.
// Phase 3: per-wave tr/l to LDS, syncthreads, 8-way combine, norm+ELU, store.
// ---------------------------------------------------------------------------
__global__ __launch_bounds__(512, 4) void k_attn(
    const int* __restrict__ adj, const ushort* __restrict__ hTf,
    const float* __restrict__ E1g, const float* __restrict__ F1g,
    const float* __restrict__ E2g, const float* __restrict__ F2g,
    float* __restrict__ out) {
  __shared__ uint maskL[ROWS][MPITCH];   // 16.4 KB
  __shared__ float tr[WPB][16][65];      // 33.3 KB
  __shared__ float lw[WPB][16];
  const int t = threadIdx.x;
  const int lane = t & 63, w = t >> 6;
  const int il = lane & 15, kg = lane >> 4;
  const int rbase = blockIdx.x * ROWS;
  const int row = rbase + il;

  // ---- Phase 1: build 16-row bitmask in LDS ----
  {
    const int4* ap = (const int4*)(adj + (size_t)rbase * NN);
#pragma unroll 4
    for (int it = 0; it < (ROWS * NN / 4) / 512; ++it) {
      const int qq = t + it * 512;
      const int4 v = ap[qq];
      uint nib = (uint)(v.x & 1) | ((uint)(v.y & 1) << 1) |
                 ((uint)(v.z & 1) << 2) | ((uint)(v.w & 1) << 3);
      uint b = nib | ((uint)__shfl_xor((int)nib, 1) << 4);
      b |= (uint)__shfl_xor((int)b, 2) << 8;
      b |= (uint)__shfl_xor((int)b, 4) << 16;
      if ((lane & 7) == 0) maskL[qq >> 11][(qq >> 3) & 255] = b;
    }
  }
  const float e1 = E1g[row], f1 = F1g[row];
  __syncthreads();

  // ---- Phase 2: register-direct P + PV ----
  bf16x8 ones;
#pragma unroll
  for (int e = 0; e < 8; ++e) ones[e] = (short)0x3F80;  // bf16 1.0
  f32x4 acc[4] = {{0,0,0,0},{0,0,0,0},{0,0,0,0},{0,0,0,0}};
  f32x4 accl = {0.f, 0.f, 0.f, 0.f};
  const int jb0 = w * 1024 + kg * 8;

#pragma unroll 2
  for (int c = 0; c < CPW; ++c) {
    const uint bits = maskL[il][w * 32 + c] >> (kg * 8);
    const int jo = jb0 + c * 32;
    const float4 e2a = *(const float4*)(E2g + jo);
    const float4 e2b = *(const float4*)(E2g + jo + 4);
    const float4 f2a = *(const float4*)(F2g + jo);
    const float4 f2b = *(const float4*)(F2g + jo + 4);
    bf16x8 pb;
    pb[0] = (bits & 1u)   ? (short)f2bf(fmaxf(e1 * e2a.x, f1 * f2a.x)) : (short)0;
    pb[1] = (bits & 2u)   ? (short)f2bf(fmaxf(e1 * e2a.y, f1 * f2a.y)) : (short)0;
    pb[2] = (bits & 4u)   ? (short)f2bf(fmaxf(e1 * e2a.z, f1 * f2a.z)) : (short)0;
    pb[3] = (bits & 8u)   ? (short)f2bf(fmaxf(e1 * e2a.w, f1 * f2a.w)) : (short)0;
    pb[4] = (bits & 16u)  ? (short)f2bf(fmaxf(e1 * e2b.x, f1 * f2b.x)) : (short)0;
    pb[5] = (bits & 32u)  ? (short)f2bf(fmaxf(e1 * e2b.y, f1 * f2b.y)) : (short)0;
    pb[6] = (bits & 64u)  ? (short)f2bf(fmaxf(e1 * e2b.z, f1 * f2b.z)) : (short)0;
    pb[7] = (bits & 128u) ? (short)f2bf(fmaxf(e1 * e2b.w, f1 * f2b.w)) : (short)0;
    accl = __builtin_amdgcn_mfma_f32_16x16x32_bf16(ones, pb, accl, 0, 0, 0);
    const int j32 = w * 32 + c;
#pragma unroll
    for (int f = 0; f < 4; ++f) {
      const bf16x8 hv =
          *(const bf16x8*)(hTf + ((size_t)(f * 256 + j32) * 64 + lane) * 8);
      acc[f] = __builtin_amdgcn_mfma_f32_16x16x32_bf16(hv, pb, acc[f], 0, 0, 0);
    }
  }
  // ---- Phase 3: combine ----
  // lane holds i = rbase+il (col n), d = f*16 + kg*4 + r (row m)
#pragma unroll
  for (int f = 0; f < 4; ++f)
#pragma unroll
    for (int r = 0; r < 4; ++r) tr[w][il][f * 16 + kg * 4 + r] = acc[f][r];
  if (lane < 16) lw[w][il] = accl[0];  // l_i (same across regs/kg)
  __syncthreads();
#pragma unroll
  for (int k = 0; k < (ROWS * FF) / 512; ++k) {
    const int idx = t + k * 512;
    const int r = idx >> 6, d = idx & 63;
    float s = 0.f, L = 0.f;
#pragma unroll
    for (int ww = 0; ww < WPB; ++ww) {
      s += tr[ww][r][d];
      L += lw[ww][r];
    }
    const float x = s / fmaxf(L, 1e-30f);
    out[(size_t)(rbase + r) * FF + d] = x > 0.f ? x : expm1f(x);
  }
}

extern "C" void kernel_launch(void* const* d_in, const int* in_sizes, int n_in,
                              void* d_out, int out_size, void* d_ws, size_t ws_size,
                              hipStream_t stream) {
  const float* feat = (const float*)d_in[0];
  const int* adj = (const int*)d_in[1];
  const float* W = (const float*)d_in[2];
  const float* a = (const float*)d_in[3];
  float* out = (float*)d_out;

  ushort* hTf = (ushort*)d_ws;                      // 64*8192 bf16 = 1 MB
  ushort* WT = hTf + (size_t)FF * NN;               // 64*256 bf16 = 32 KB
  float* E1 = (float*)(WT + (size_t)FF * DD);       // 8192 f32 each
  float* F1 = E1 + NN;
  float* E2 = F1 + NN;
  float* F2 = E2 + NN;

  hipLaunchKernelGGL(k_pre, dim3(DD * FF / 1024), dim3(256), 0, stream, W, WT);
  hipLaunchKernelGGL(k_h, dim3(NN / 16), dim3(256), 0, stream, feat, WT, a, hTf,
                     E1, F1, E2, F2);
  hipLaunchKernelGGL(k_attn, dim3(NN / ROWS), dim3(512), 0, stream,
                     adj, hTf, E1, F1, E2, F2, out);
}